// Round 8
// baseline (496.298 us; speedup 1.0000x reference)
//
#include <hip/hip_runtime.h>

#define KCODES 512
#define DIM 64
#define NB 32
#define NH 64
#define NW 64
#define NPTS (NB*NH*NW)     // 131072
#define HW (NH*NW)          // 4096

// ---- output layout (floats) ----
#define O_OUT  0
#define O_LOSS 8388608
#define O_IDX  8388609
#define O_EMB  8519681
#define O_M    8552449
#define O_MM   8585217

// ---- workspace layout (floats) ----
#define W_DM   0
#define W_CNT  (KCODES*DIM)         // 32768
#define W_LOSS (W_CNT + KCODES)     // 33280
#define W_NEWM (W_LOSS + 1)         // 33281
#define W_TOTAL (W_NEWM + KCODES)   // 33793

// Register-resident codebook: thread t holds codes t and t+256 entirely in
// VGPRs (128 regs, statically indexed). Point vector x broadcast via
// WAVE-UNIFORM loads (one SGPR base + 64 immediate-offset s_load_dword).
// Inner loop: 2 interleaved FMA chains (SGPR x VGPR), ZERO LDS, ZERO vector
// loads -> VALU-bound (~55us floor) instead of r6/r7's LDS/latency-bound 190+.
// FMA order = r6/r7 (sequential d, fma(x,e,acc)) -> scores bit-identical.
__global__ __launch_bounds__(256, 2) void assign_kernel(
    const float* __restrict__ enc, const float* __restrict__ emb,
    float* __restrict__ out, float* __restrict__ ws)
{
    __shared__ unsigned int Lu[4][256];
    __shared__ int          Li[4][256];
    __shared__ float        red[4];

    const int t  = threadIdx.x;
    const int l  = t & 63;
    const int wv = t >> 6;

    float ca[DIM], cb[DIM];
    const float* ea = emb + t*DIM;
    const float* eb = emb + (t+256)*DIM;
    #pragma unroll
    for (int d = 0; d < DIM; ++d) { ca[d] = ea[d]; cb[d] = eb[d]; }
    float cn0 = 0.f, cn1 = 0.f;
    #pragma unroll
    for (int d = 0; d < DIM; ++d) {
        cn0 = fmaf(ca[d], ca[d], cn0);
        cn1 = fmaf(cb[d], cb[d], cn1);
    }

    const int P0 = blockIdx.x * 256;

    for (int p = 0; p < 256; ++p) {
        const int P = P0 + p;
        // x[d] = enc[b*64*HW + d*HW + h*64 + w]; all-uniform address
        const float* xb = enc + ((size_t)(P >> 12))*(64*HW)
                              + ((size_t)((P >> 6) & 63))*64 + (P & 63);
        float a0 = 0.f, a1 = 0.f;
        #pragma unroll
        for (int d = 0; d < DIM; ++d) {
            float xd = xb[(size_t)d*HW];          // s_load (imm offset d*16KB)
            a0 = fmaf(xd, ca[d], a0);             // 2 indep chains: 4cyc dep
            a1 = fmaf(xd, cb[d], a1);             // latency covered at 2cyc issue
        }
        float d0 = cn0 - 2.f*a0;
        float d1 = cn1 - 2.f*a1;
        float bd = (d0 <= d1) ? d0 : d1;          // <= : lower idx wins tie
        int   bi = (d0 <= d1) ? t : (t + 256);
        // order-preserving u32 map (no NaNs here)
        unsigned int u = __float_as_uint(bd);
        u = ((int)u < 0) ? ~u : (u | 0x80000000u);
        unsigned int umin = u;
        #pragma unroll
        for (int off = 1; off < 64; off <<= 1) {
            unsigned int o = __shfl_xor(umin, off, 64);
            umin = (o < umin) ? o : umin;
        }
        unsigned long long m = __ballot(u == umin);
        int widx;
        if (__popcll(m) == 1) {                   // almost always
            int fl = (int)__ffsll(m) - 1;
            widx = __shfl(bi, fl, 64);
        } else {                                  // exact tie: first-min index
            int ci = (u == umin) ? bi : 0x7fffffff;
            #pragma unroll
            for (int off = 1; off < 64; off <<= 1) {
                int o = __shfl_xor(ci, off, 64);
                ci = (o < ci) ? o : ci;
            }
            widx = ci;
        }
        if (l == 0) { Lu[wv][p] = umin; Li[wv][p] = widx; }
    }
    __syncthreads();

    // combine the 4 waves' candidates; lexicographic (dist, idx) = first-min
    {
        const int p = t;
        unsigned int bu = Lu[0][p]; int bi2 = Li[0][p];
        #pragma unroll
        for (int v = 1; v < 4; ++v) {
            unsigned int u2 = Lu[v][p]; int i2 = Li[v][p];
            if (u2 < bu || (u2 == bu && i2 < bi2)) { bu = u2; bi2 = i2; }
        }
        out[O_IDX + (size_t)P0 + p] = (float)bi2;
        float bf = __uint_as_float(((int)bu < 0) ? (bu & 0x7fffffffu) : ~bu);
        #pragma unroll
        for (int off = 32; off >= 1; off >>= 1) bf += __shfl_down(bf, off, 64);
        if (l == 0) red[wv] = bf;
    }
    __syncthreads();
    if (t == 0) atomicAdd(&ws[W_LOSS], red[0]+red[1]+red[2]+red[3]);
}

// 256 blocks x 512 threads (8 waves; wave = one (b,h) row of 64 points).
// Fuses: dm/cnt LDS accumulation + quantized-out store + |x|^2 loss part.
// No staging tiles (direct strided reads, 16x16B segments/instr, L1-local);
// LDS = dmL+cnt = 135 KB -> 1 block/CU, 8 waves for latency hiding.
__global__ __launch_bounds__(512, 1) void scatter_kernel(
    const float* __restrict__ enc, const float* __restrict__ emb,
    float* __restrict__ out, float* __restrict__ ws)
{
    __shared__ float dmL[KCODES][DIM+1];
    __shared__ float cntL[KCODES];
    __shared__ float redL[8];

    const int t  = threadIdx.x;
    const int w  = t & 63;
    const int wv = t >> 6;
    const int pg = w >> 4, dl = w & 15;

    float* dmf = &dmL[0][0];
    for (int i = t; i < KCODES*(DIM+1); i += 512) dmf[i] = 0.f;
    if (t < KCODES) cntL[t] = 0.f;
    __syncthreads();

    const int R = blockIdx.x * 8 + wv;
    const int b = R >> 6, h = R & 63;
    const float* base  = enc + (size_t)b*(64*HW) + (size_t)h*64;
    float*       obase = out + O_OUT + (size_t)b*(64*HW) + (size_t)h*64;

    const int bidx = (int)out[O_IDX + (size_t)R*64 + w];
    atomicAdd(&cntL[bidx], 1.0f);
    float xsq = 0.f;

    #pragma unroll
    for (int c = 0; c < 4; ++c) {
        #pragma unroll
        for (int jj = 0; jj < 16; ++jj) {
            int p  = jj*4 + pg;                  // 4 pts x 16 dims per instr
            int kb = __shfl(bidx, p, 64);
            int d  = c*16 + dl;
            float xv = base[(size_t)d*HW + p];
            atomicAdd(&dmL[kb][d], xv);          // same-code lanes hit diff dims
            xsq = fmaf(xv, xv, xsq);
            obase[(size_t)d*HW + p] = emb[kb*64 + d];   // 4x64B gather runs
        }
    }

    #pragma unroll
    for (int off = 32; off >= 1; off >>= 1) xsq += __shfl_down(xsq, off, 64);
    if (w == 0) redL[wv] = xsq;
    __syncthreads();
    if (t == 0) {
        float s = 0.f;
        #pragma unroll
        for (int v = 0; v < 8; ++v) s += redL[v];
        atomicAdd(&ws[W_LOSS], s);
    }

    // flush: wave wv owns 64 rows; lane = dim (coalesced 256B atomic runs)
    for (int k = wv*64; k < wv*64 + 64; ++k) {
        float c = cntL[k];
        if (c == 0.f) continue;                  // wave-uniform branch
        atomicAdd(&ws[W_DM + k*64 + w], dmL[k][w]);
        if (w == 0) atomicAdd(&ws[W_CNT + k], c);
    }
}

__global__ void finalizeA(const float* __restrict__ emaM,
                          float* __restrict__ out, float* __restrict__ ws)
{
    __shared__ float red[512];
    int k = threadIdx.x;
    float nM = 0.99f * emaM[k] + 0.01f * ws[W_CNT + k];
    red[k] = nM;
    __syncthreads();
    for (int s = 256; s >= 1; s >>= 1) {
        if (k < s) red[k] += red[k + s];
        __syncthreads();
    }
    float Ntot = red[0];
    float sm = (nM + 1e-5f) / (Ntot + 1e-5f * (float)KCODES) * Ntot;
    ws[W_NEWM + k] = sm;
    out[O_MM + k] = sm;
    if (k == 0) out[O_LOSS] = 0.25f * ws[W_LOSS] / (float)((size_t)NPTS * DIM);
}

__global__ void finalizeB(const float* __restrict__ emam,
                          float* __restrict__ out, const float* __restrict__ ws)
{
    int i = blockIdx.x * blockDim.x + threadIdx.x;
    int k = i >> 6;
    float nm = 0.99f * emam[i] + 0.01f * ws[W_DM + i];
    out[O_M + i] = nm;
    out[O_EMB + i] = nm / ws[W_NEWM + k];
}

extern "C" void kernel_launch(void* const* d_in, const int* in_sizes, int n_in,
                              void* d_out, int out_size, void* d_ws, size_t ws_size,
                              hipStream_t stream)
{
    const float* enc  = (const float*)d_in[0];
    const float* emb  = (const float*)d_in[1];
    const float* emam = (const float*)d_in[2];
    const float* emaM = (const float*)d_in[3];
    float* out = (float*)d_out;
    float* ws  = (float*)d_ws;

    hipMemsetAsync(ws, 0, (size_t)W_TOTAL * sizeof(float), stream);
    assign_kernel<<<NPTS/256, 256, 0, stream>>>(enc, emb, out, ws);   // 512 blocks
    scatter_kernel<<<256, 512, 0, stream>>>(enc, emb, out, ws);
    finalizeA<<<1, 512, 0, stream>>>(emaM, out, ws);
    finalizeB<<<(KCODES*DIM)/256, 256, 0, stream>>>(emam, out, ws);
}

// Round 9
// 243.474 us; speedup vs baseline: 2.0384x; 2.0384x over previous
//
#include <hip/hip_runtime.h>

#define KCODES 512
#define DIM 64
#define NB 32
#define NH 64
#define NW 64
#define NPTS (NB*NH*NW)     // 131072
#define HW (NH*NW)          // 4096

// ---- output layout (floats) ----
#define O_OUT  0
#define O_LOSS 8388608
#define O_IDX  8388609
#define O_EMB  8519681
#define O_M    8552449
#define O_MM   8585217

// ---- workspace layout (floats) ----
#define W_DM   0
#define W_CNT  (KCODES*DIM)         // 32768
#define W_LOSS (W_CNT + KCODES)     // 33280
#define W_NEWM (W_LOSS + 1)         // 33281
#define W_C    (W_NEWM + KCODES)    // 33793
#define W_TOTAL (W_C + KCODES)      // 34305

#define XPAD 68
#define EPAD 68

__global__ void cnorm_kernel(const float* __restrict__ emb, float* __restrict__ ws) {
    int k = blockIdx.x * blockDim.x + threadIdx.x;
    if (k >= KCODES) return;
    float s = 0.f;
    #pragma unroll
    for (int d = 0; d < DIM; ++d) { float v = emb[k*DIM + d]; s += v*v; }
    ws[W_C + k] = s;
}

// Register-tiled fp32 GEMM (128 pts x 512 cw / block, 8x8 microtile) -- the
// proven r6 structure. vs r7: NO register prefetch (it spilled: WRITE_SIZE
// 93MB), NO epilogue store/loss (moved to scatter_kernel). Output: idx only.
// FMA order identical to r6/r7 -> scores bit-identical -> counts unchanged.
__global__ __launch_bounds__(256, 2) void assign_kernel(
    const float* __restrict__ enc, const float* __restrict__ emb,
    float* __restrict__ out, float* __restrict__ ws)
{
    __shared__ float XL[128*XPAD];   // [point][d]
    __shared__ float EL[128*EPAD];   // [cw][d]
    __shared__ float cnT[128];
    __shared__ int   bestI[128];

    const int t  = threadIdx.x;
    const int tx = t & 15;
    const int ty = t >> 4;
    const int wv = t >> 6, w = t & 63;
    const int R0 = blockIdx.x * 2;

    // stage X: thread = (point w, dim-quad); 4 coalesced b32 loads ->
    // one ds_write_b128 (conflict-audited in r7: residual 262K cycles, ~4us)
    #pragma unroll
    for (int r2 = 0; r2 < 2; ++r2) {
        int R = R0 + r2, b = R >> 6, h = R & 63;
        const float* base = enc + (size_t)b*64*HW + (size_t)h*64 + w;
        int p = r2*64 + w;
        #pragma unroll
        for (int it = 0; it < 4; ++it) {
            int d0 = (it*4 + wv)*4;
            float4 v = make_float4(base[(size_t)(d0+0)*HW], base[(size_t)(d0+1)*HW],
                                   base[(size_t)(d0+2)*HW], base[(size_t)(d0+3)*HW]);
            *(float4*)(&XL[p*XPAD + d0]) = v;
        }
    }

    float best[8]; int bidx[8];
    #pragma unroll
    for (int i = 0; i < 8; ++i) { best[i] = 3.402823466e38f; bidx[i] = 0; }

    for (int tile = 0; tile < 4; ++tile) {
        __syncthreads();             // prior tile's EL reads done
        const float* esrc = emb + (size_t)tile*128*64;
        #pragma unroll
        for (int it = 0; it < 8; ++it) {
            int idx = t + it*256;
            *(float4*)(&EL[(idx >> 4)*EPAD + (idx & 15)*4]) =
                *(const float4*)(esrc + (idx >> 4)*64 + (idx & 15)*4);
        }
        if (t < 128) cnT[t] = ws[W_C + tile*128 + t];
        __syncthreads();

        float acc[8][8];
        #pragma unroll
        for (int i = 0; i < 8; ++i)
            #pragma unroll
            for (int j = 0; j < 8; ++j) acc[i][j] = 0.f;

        for (int c = 0; c < 16; ++c) {
            float4 xf[8], ef[8];
            #pragma unroll
            for (int i = 0; i < 8; ++i) {    // 16-lane broadcast reads
                int p = 2*ty + (i&1) + 32*(i>>1);
                xf[i] = *(const float4*)(&XL[p*XPAD + c*4]);
            }
            #pragma unroll
            for (int j = 0; j < 8; ++j) {    // 16 rows: 2 addrs/quad = free
                int r = tx + 16*j;
                ef[j] = *(const float4*)(&EL[r*EPAD + c*4]);
            }
            #pragma unroll
            for (int i = 0; i < 8; ++i)
                #pragma unroll
                for (int j = 0; j < 8; ++j) {
                    acc[i][j] = fmaf(xf[i].x, ef[j].x, acc[i][j]);
                    acc[i][j] = fmaf(xf[i].y, ef[j].y, acc[i][j]);
                    acc[i][j] = fmaf(xf[i].z, ef[j].z, acc[i][j]);
                    acc[i][j] = fmaf(xf[i].w, ef[j].w, acc[i][j]);
                }
        }

        #pragma unroll
        for (int j = 0; j < 8; ++j) {
            int k = tile*128 + tx + 16*j;
            float cn = cnT[tx + 16*j];
            #pragma unroll
            for (int i = 0; i < 8; ++i) {
                float s = cn - 2.f*acc[i][j];
                if (s < best[i] || (s == best[i] && k < bidx[i])) { best[i] = s; bidx[i] = k; }
            }
        }
    }

    // cross-lane argmin over the 16 tx-lanes sharing each point
    #pragma unroll
    for (int i = 0; i < 8; ++i) {
        float b = best[i]; int kx = bidx[i];
        #pragma unroll
        for (int off = 1; off < 16; off <<= 1) {
            float ob = __shfl_xor(b, off, 64);
            int   ok = __shfl_xor(kx, off, 64);
            if (ob < b || (ob == b && ok < kx)) { b = ob; kx = ok; }
        }
        if (tx == 0) bestI[2*ty + (i&1) + 32*(i>>1)] = kx;
    }
    __syncthreads();
    if (t < 128) out[O_IDX + (size_t)R0*64 + t] = (float)bestI[t];
}

// 256 blocks x 512 threads (8 waves; wave = one (b,h) row of 64 points).
// Fuses: dm/cnt LDS accumulation + quantized-out store + commitment loss.
__global__ __launch_bounds__(512, 1) void scatter_kernel(
    const float* __restrict__ enc, const float* __restrict__ emb,
    float* __restrict__ out, float* __restrict__ ws)
{
    __shared__ float dmL[KCODES][DIM+1];
    __shared__ float cntL[KCODES];
    __shared__ float redL[8];

    const int t  = threadIdx.x;
    const int w  = t & 63;
    const int wv = t >> 6;
    const int pg = w >> 4, dl = w & 15;

    float* dmf = &dmL[0][0];
    for (int i = t; i < KCODES*(DIM+1); i += 512) dmf[i] = 0.f;
    if (t < KCODES) cntL[t] = 0.f;
    __syncthreads();

    const int R = blockIdx.x * 8 + wv;
    const int b = R >> 6, h = R & 63;
    const float* base  = enc + (size_t)b*(64*HW) + (size_t)h*64;
    float*       obase = out + O_OUT + (size_t)b*(64*HW) + (size_t)h*64;

    const int bidx = (int)out[O_IDX + (size_t)R*64 + w];
    atomicAdd(&cntL[bidx], 1.0f);
    float lsum = 0.f;

    #pragma unroll
    for (int c = 0; c < 4; ++c) {
        #pragma unroll
        for (int jj = 0; jj < 16; ++jj) {
            int p  = jj*4 + pg;                  // 4 pts x 16 dims per instr
            int kb = __shfl(bidx, p, 64);
            int d  = c*16 + dl;
            float xv = base[(size_t)d*HW + p];
            atomicAdd(&dmL[kb][d], xv);          // same-code lanes hit diff dims
            float q = emb[kb*64 + d];            // 4x64B gather runs
            obase[(size_t)d*HW + p] = q;
            float df = q - xv;
            lsum = fmaf(df, df, lsum);
        }
    }

    #pragma unroll
    for (int off = 32; off >= 1; off >>= 1) lsum += __shfl_down(lsum, off, 64);
    if (w == 0) redL[wv] = lsum;
    __syncthreads();
    if (t == 0) {
        float s = 0.f;
        #pragma unroll
        for (int v = 0; v < 8; ++v) s += redL[v];
        atomicAdd(&ws[W_LOSS], s);
    }

    // flush: wave wv owns 64 rows; lane = dim (coalesced 256B atomic runs)
    for (int k = wv*64; k < wv*64 + 64; ++k) {
        float c = cntL[k];
        if (c == 0.f) continue;                  // wave-uniform branch
        atomicAdd(&ws[W_DM + k*64 + w], dmL[k][w]);
        if (w == 0) atomicAdd(&ws[W_CNT + k], c);
    }
}

__global__ void finalizeA(const float* __restrict__ emaM,
                          float* __restrict__ out, float* __restrict__ ws)
{
    __shared__ float red[512];
    int k = threadIdx.x;
    float nM = 0.99f * emaM[k] + 0.01f * ws[W_CNT + k];
    red[k] = nM;
    __syncthreads();
    for (int s = 256; s >= 1; s >>= 1) {
        if (k < s) red[k] += red[k + s];
        __syncthreads();
    }
    float Ntot = red[0];
    float sm = (nM + 1e-5f) / (Ntot + 1e-5f * (float)KCODES) * Ntot;
    ws[W_NEWM + k] = sm;
    out[O_MM + k] = sm;
    if (k == 0) out[O_LOSS] = 0.25f * ws[W_LOSS] / (float)((size_t)NPTS * DIM);
}

__global__ void finalizeB(const float* __restrict__ emam,
                          float* __restrict__ out, const float* __restrict__ ws)
{
    int i = blockIdx.x * blockDim.x + threadIdx.x;
    int k = i >> 6;
    float nm = 0.99f * emam[i] + 0.01f * ws[W_DM + i];
    out[O_M + i] = nm;
    out[O_EMB + i] = nm / ws[W_NEWM + k];
}

extern "C" void kernel_launch(void* const* d_in, const int* in_sizes, int n_in,
                              void* d_out, int out_size, void* d_ws, size_t ws_size,
                              hipStream_t stream)
{
    const float* enc  = (const float*)d_in[0];
    const float* emb  = (const float*)d_in[1];
    const float* emam = (const float*)d_in[2];
    const float* emaM = (const float*)d_in[3];
    float* out = (float*)d_out;
    float* ws  = (float*)d_ws;

    hipMemsetAsync(ws, 0, (size_t)W_TOTAL * sizeof(float), stream);
    cnorm_kernel<<<2, 256, 0, stream>>>(emb, ws);
    assign_kernel<<<NPTS/128, 256, 0, stream>>>(enc, emb, out, ws);   // 1024 blocks
    scatter_kernel<<<256, 512, 0, stream>>>(enc, emb, out, ws);
    finalizeA<<<1, 512, 0, stream>>>(emaM, out, ws);
    finalizeB<<<(KCODES*DIM)/256, 256, 0, stream>>>(emam, out, ws);
}